// Round 5
// baseline (560.192 us; speedup 1.0000x reference)
//
#include <hip/hip_runtime.h>

typedef __bf16 bf16_t;
typedef bf16_t bf16x8 __attribute__((ext_vector_type(8)));
typedef float f32x4 __attribute__((ext_vector_type(4)));

#define MFMA16(a, b, c) __builtin_amdgcn_mfma_f32_16x16x32_bf16((a), (b), (c), 0, 0, 0)

// ---------------- fill: sigma plane (1.0 / 0.25), mus[0]=0, zs[0]=noise0 ----------------
__global__ void fill_out_kernel(const float* __restrict__ noise0, float* __restrict__ out) {
  const int SLAB = 2048 * 256;   // one (B,Z) slab
  const int SZ = 17 * SLAB;      // one output plane
  int i = (blockIdx.x * blockDim.x + threadIdx.x) * 4;
  if (i >= 19 * SLAB) return;
  float4 v;
  int dst;
  if (i < 17 * SLAB) {                       // sigmas plane (s=2)
    float x = (i < SLAB) ? 1.0f : 0.25f;
    v = make_float4(x, x, x, x);
    dst = 2 * SZ + i;
  } else if (i < 18 * SLAB) {                // mus (s=1), t=0 slab
    v = make_float4(0.f, 0.f, 0.f, 0.f);
    dst = SZ + (i - 17 * SLAB);
  } else {                                   // zs (s=0), t=0 slab = noise0
    v = *(const float4*)(noise0 + (i - 18 * SLAB));
    dst = i - 18 * SLAB;
  }
  *(float4*)(out + dst) = v;
}

// ---------------- f32 -> bf16 plain cast ----------------
__global__ void cast_bf16_kernel(const float* __restrict__ src, bf16_t* __restrict__ dst, int n) {
  int i = (blockIdx.x * blockDim.x + threadIdx.x) * 4;
  if (i >= n) return;
#pragma unroll
  for (int j = 0; j < 4; ++j) dst[i + j] = (bf16_t)src[i + j];
}

// ---------------- pack KxN f32 weight into MFMA B-fragment order ----------------
// dst[((kt*NT + nt)*64 + lane)*8 + j] = src[kt*32 + 8*(lane>>4) + j][nt*16 + (lane&15)]
__global__ void pack_b_kernel(const float* __restrict__ src, bf16_t* __restrict__ dst, int K, int N) {
  int tid = blockIdx.x * blockDim.x + threadIdx.x;   // one per (kt, nt, lane)
  int NT = N >> 4;
  if (tid >= (K >> 5) * NT * 64) return;
  int l = tid & 63;
  int grp = tid >> 6;
  int nt = grp % NT, kt = grp / NT;
  int r = l & 15, g = l >> 4;
  const float* s = src + (size_t)(kt * 32 + 8 * g) * N + nt * 16 + r;
  bf16_t* d = dst + (size_t)tid * 8;
#pragma unroll
  for (int j = 0; j < 8; ++j) d[j] = (bf16_t)s[(size_t)j * N];
}

// ---------------- generic bf16 MFMA GEMM: C = A(MxK, bf16 row-major) @ Bpacked (+bias) ----------------
__global__ __launch_bounds__(256) void gemm_bf16_kernel(
    const bf16_t* __restrict__ A, const bf16_t* __restrict__ Bp,
    const float* __restrict__ bias, float* __restrict__ C,
    int M, int N, int K, int useBias)
{
  int l = threadIdx.x & 63, w = threadIdx.x >> 6;
  int r = l & 15, g = l >> 4;
  int rowbase = blockIdx.x * 64 + w * 16;
  int colbase = blockIdx.y * 64;
  int NT = N >> 4;
  const bf16x8* Bv = (const bf16x8*)Bp;
  f32x4 acc[4] = {};
  for (int kt = 0; kt < (K >> 5); ++kt) {
    bf16x8 af = *(const bf16x8*)(A + (size_t)(rowbase + r) * K + kt * 32 + 8 * g);
#pragma unroll
    for (int nt = 0; nt < 4; ++nt) {
      bf16x8 bf = Bv[(size_t)(kt * NT + (colbase >> 4) + nt) * 64 + l];
      acc[nt] = MFMA16(af, bf, acc[nt]);
    }
  }
#pragma unroll
  for (int nt = 0; nt < 4; ++nt) {
    int col = colbase + nt * 16 + r;
    float bv = useBias ? bias[col] : 0.f;
#pragma unroll
    for (int q = 0; q < 4; ++q) {
      int row = rowbase + 4 * g + q;
      C[(size_t)row * N + col] = acc[nt][q] + bv;
    }
  }
}

// ---------------- tadd[t][n] = sum_k relu((t+1)/16 * Wt[k] + bt[k]) * W0[k][n] ----------------
__global__ void tadd_kernel(const float* __restrict__ W0, const float* __restrict__ Wt,
                            const float* __restrict__ bt, float* __restrict__ tadd) {
  int t = blockIdx.x;
  int n = threadIdx.x;   // 512
  float ts = (t + 1) * 0.0625f;
  float s = 0.f;
#pragma unroll 4
  for (int k = 0; k < 768; ++k) {
    float e = fmaxf(ts * Wt[k] + bt[k], 0.f);
    s = fmaf(e, W0[k * 512 + n], s);
  }
  tadd[t * 512 + n] = s;
}

// ---------------- bo2[n] = bo[n] + sum_k bh[k]*(T3[k][n] + Wo[k][n]) ----------------
__global__ void bo2_kernel(const float* __restrict__ bh, const float* __restrict__ T3f,
                           const float* __restrict__ Wo, const float* __restrict__ bo,
                           float* __restrict__ bo2) {
  int n = threadIdx.x;   // 256
  float s = bo[n];
#pragma unroll 4
  for (int k = 0; k < 512; ++k)
    s = fmaf(bh[k], T3f[k * 256 + n] + Wo[k * 256 + n], s);
  bo2[n] = s;
}

// ---------------- main persistent loop: 128 WGs x 512 threads, 16 rows/WG, all 16 steps ----------------
// vs round 2: __launch_bounds__(512,2) -> 256 VGPR budget, and ALL weight
// fragments for each GEMM batch-prefetched into registers (one latency wait
// per GEMM instead of ~8 serialized ones). No other changes (round-3's
// nontemporal ops + merged fill reverted for correctness isolation).
__global__ __launch_bounds__(512, 2) void diffusion_main_kernel(
    const bf16_t* __restrict__ W0zp,   // [8][32][64][8]  (K=256, N=512)
    const bf16_t* __restrict__ Wfp,    // [16][16][64][8] (K=512, N=256)
    const float* __restrict__ base,    // [2048][512] = r@W0r + b0
    const float* __restrict__ tadd,    // [16][512]
    const float* __restrict__ bo2,     // [256]
    const float* __restrict__ noise0,  // [2048][256]
    const float* __restrict__ noise,   // [16][2048][256]
    float* __restrict__ out)           // [3][17][2048][256]
{
  __shared__ bf16_t zbuf[16 * 256];
  __shared__ bf16_t abuf[16 * 512];
  const int tid = threadIdx.x;
  const int w = tid >> 6, l = tid & 63;
  const int r = l & 15, g = l >> 4;
  const int brow = blockIdx.x << 4;

  // per-lane constants: GEMM1 acc-init (base), GEMM2 acc-init (bo2)
  f32x4 base_reg[4];
#pragma unroll
  for (int nt = 0; nt < 4; ++nt)
#pragma unroll
    for (int q = 0; q < 4; ++q)
      base_reg[nt][q] = base[(size_t)(brow + 4 * g + q) * 512 + w * 64 + nt * 16 + r];
  float bo_reg[2];
#pragma unroll
  for (int nt = 0; nt < 2; ++nt) bo_reg[nt] = bo2[w * 32 + nt * 16 + r];

  // z state in f32 C-layout registers; wave w owns z cols [w*32, w*32+32)
  f32x4 zst[2];
#pragma unroll
  for (int nt = 0; nt < 2; ++nt)
#pragma unroll
    for (int q = 0; q < 4; ++q)
      zst[nt][q] = noise0[(size_t)(brow + 4 * g + q) * 256 + w * 32 + nt * 16 + r];

#pragma unroll
  for (int nt = 0; nt < 2; ++nt)
#pragma unroll
    for (int q = 0; q < 4; ++q) {
      int row = 4 * g + q, col = w * 32 + nt * 16 + r;
      zbuf[(row * 256 + col) ^ ((row & 7) << 3)] = (bf16_t)zst[nt][q];
    }
  __syncthreads();

  const bf16x8* W0v = (const bf16x8*)W0zp;
  const bf16x8* Wfv = (const bf16x8*)Wfp;

#pragma unroll 1
  for (int t = 0; t < 16; ++t) {
    // prefetch eps + tadd early (latency hides under GEMM1)
    float ep[2][4];
#pragma unroll
    for (int nt = 0; nt < 2; ++nt)
#pragma unroll
      for (int q = 0; q < 4; ++q)
        ep[nt][q] = noise[((size_t)t * 2048 + brow + 4 * g + q) * 256 + w * 32 + nt * 16 + r];
    float tv[4];
#pragma unroll
    for (int nt = 0; nt < 4; ++nt) tv[nt] = tadd[t * 512 + w * 64 + nt * 16 + r];

    // batch-prefetch ALL GEMM1 weight fragments (32 x 16B in flight)
    bf16x8 wf1[8][4];
#pragma unroll
    for (int kt = 0; kt < 8; ++kt)
#pragma unroll
      for (int nt = 0; nt < 4; ++nt)
        wf1[kt][nt] = W0v[(size_t)(kt * 32 + w * 4 + nt) * 64 + l];

    // z A-fragments from swizzled LDS (row = lane&15, k = kt*32 + 8*(lane>>4) + j)
    bf16x8 zf[8];
#pragma unroll
    for (int kt = 0; kt < 8; ++kt) {
      int e = (r * 256 + kt * 32 + 8 * g) ^ ((r & 7) << 3);
      zf[kt] = *(const bf16x8*)&zbuf[e];
    }

    // GEMM1: h1 = z @ W0z, acc pre-initialized with base + tadd[t]
    f32x4 acc1[4];
#pragma unroll
    for (int nt = 0; nt < 4; ++nt)
#pragma unroll
      for (int q = 0; q < 4; ++q) acc1[nt][q] = base_reg[nt][q] + tv[nt];
#pragma unroll
    for (int kt = 0; kt < 8; ++kt)
#pragma unroll
      for (int nt = 0; nt < 4; ++nt)
        acc1[nt] = MFMA16(zf[kt], wf1[kt][nt], acc1[nt]);

    // a = relu(h1) -> abuf (bf16, XOR-swizzled)
#pragma unroll
    for (int nt = 0; nt < 4; ++nt)
#pragma unroll
      for (int q = 0; q < 4; ++q) {
        int row = 4 * g + q, col = w * 64 + nt * 16 + r;
        abuf[(row * 512 + col) ^ ((row & 7) << 3)] = (bf16_t)fmaxf(acc1[nt][q], 0.f);
      }

    // batch-prefetch ALL GEMM2 weight fragments (latency drains across the barrier)
    bf16x8 wf2[16][2];
#pragma unroll
    for (int kt = 0; kt < 16; ++kt)
#pragma unroll
      for (int nt = 0; nt < 2; ++nt)
        wf2[kt][nt] = Wfv[(size_t)(kt * 16 + w * 2 + nt) * 64 + l];

    __syncthreads();   // B1: abuf complete; zbuf reads of this step done

    // GEMM2: score = a @ Wf + bo2
    f32x4 acc2[2];
#pragma unroll
    for (int nt = 0; nt < 2; ++nt)
#pragma unroll
      for (int q = 0; q < 4; ++q) acc2[nt][q] = bo_reg[nt];
#pragma unroll
    for (int kt = 0; kt < 16; ++kt) {
      int e = (r * 512 + kt * 32 + 8 * g) ^ ((r & 7) << 3);
      bf16x8 af = *(const bf16x8*)&abuf[e];
#pragma unroll
      for (int nt = 0; nt < 2; ++nt)
        acc2[nt] = MFMA16(af, wf2[kt][nt], acc2[nt]);
    }

    // z update + write zs[t+1], mus[t+1]
#pragma unroll
    for (int nt = 0; nt < 2; ++nt)
#pragma unroll
      for (int q = 0; q < 4; ++q) {
        int row = 4 * g + q, col = w * 32 + nt * 16 + r;
        int grow = brow + row;
        float mu = fmaf(acc2[nt][q], 0.0625f, zst[nt][q]);   // z + score*dt
        float zn = fmaf(ep[nt][q], 0.25f, mu);               // + sqrt(dt)*eps
        zst[nt][q] = zn;
        out[((size_t)(t + 1) * 2048 + grow) * 256 + col] = zn;            // zs plane
        out[((size_t)(17 + t + 1) * 2048 + grow) * 256 + col] = mu;       // mus plane
        zbuf[(row * 256 + col) ^ ((row & 7) << 3)] = (bf16_t)zn;
      }
    __syncthreads();   // B2: zbuf(t+1) complete before next step's reads
  }
}

extern "C" void kernel_launch(void* const* d_in, const int* in_sizes, int n_in,
                              void* d_out, int out_size, void* d_ws, size_t ws_size,
                              hipStream_t stream) {
  const float* r   = (const float*)d_in[0];
  const float* n0  = (const float*)d_in[1];
  const float* nz  = (const float*)d_in[2];
  const float* W0  = (const float*)d_in[3];
  const float* b0  = (const float*)d_in[4];
  const float* Wh  = (const float*)d_in[5];
  const float* bh  = (const float*)d_in[6];
  const float* Wo  = (const float*)d_in[7];
  const float* bo  = (const float*)d_in[8];
  const float* Wt  = (const float*)d_in[9];
  const float* bt  = (const float*)d_in[10];
  float* out = (float*)d_out;

  char* ws = (char*)d_ws;
  size_t off = 0;
  auto alloc = [&](size_t bytes) -> char* {
    char* p = ws + off;
    off += (bytes + 255) & ~(size_t)255;
    return p;
  };
  bf16_t* r_bf  = (bf16_t*)alloc((size_t)2048 * 512 * 2);
  bf16_t* Wh_bf = (bf16_t*)alloc((size_t)512 * 512 * 2);
  bf16_t* W0zp  = (bf16_t*)alloc((size_t)256 * 512 * 2);
  bf16_t* W0rp  = (bf16_t*)alloc((size_t)512 * 512 * 2);
  bf16_t* Wop   = (bf16_t*)alloc((size_t)512 * 256 * 2);
  float*  T3f   = (float*) alloc((size_t)512 * 256 * 4);
  bf16_t* T3p   = (bf16_t*)alloc((size_t)512 * 256 * 2);
  float*  Wff   = (float*) alloc((size_t)512 * 256 * 4);
  bf16_t* Wfp   = (bf16_t*)alloc((size_t)512 * 256 * 2);
  float*  baseb = (float*) alloc((size_t)2048 * 512 * 4);
  float*  taddb = (float*) alloc((size_t)16 * 512 * 4);
  float*  bo2b  = (float*) alloc((size_t)256 * 4);
  if (off > ws_size) return;   // workspace too small — bail (will fail validation loudly)

  // constant output regions (sigmas, mus[0], zs[0])
  fill_out_kernel<<<9728, 256, 0, stream>>>(n0, out);

  // casts
  cast_bf16_kernel<<<1024, 256, 0, stream>>>(r, r_bf, 2048 * 512);
  cast_bf16_kernel<<<256, 256, 0, stream>>>(Wh, Wh_bf, 512 * 512);

  // weight packs (MFMA B-fragment order)
  pack_b_kernel<<<64, 256, 0, stream>>>(W0, W0zp, 256, 512);              // W0[0:256]
  pack_b_kernel<<<128, 256, 0, stream>>>(W0 + 256 * 512, W0rp, 512, 512); // W0[256:768]
  pack_b_kernel<<<64, 256, 0, stream>>>(Wo, Wop, 512, 256);

  // Wf = Wh @ (Wh @ Wo), bo2 = bh@T3 + bh@Wo + bo
  gemm_bf16_kernel<<<dim3(8, 4), 256, 0, stream>>>(Wh_bf, Wop, nullptr, T3f, 512, 256, 512, 0);
  pack_b_kernel<<<64, 256, 0, stream>>>(T3f, T3p, 512, 256);
  gemm_bf16_kernel<<<dim3(8, 4), 256, 0, stream>>>(Wh_bf, T3p, nullptr, Wff, 512, 256, 512, 0);
  pack_b_kernel<<<64, 256, 0, stream>>>(Wff, Wfp, 512, 256);

  // base = r @ W0r + b0
  gemm_bf16_kernel<<<dim3(32, 8), 256, 0, stream>>>(r_bf, W0rp, b0, baseb, 2048, 512, 512, 1);

  tadd_kernel<<<16, 512, 0, stream>>>(W0, Wt, bt, taddb);
  bo2_kernel<<<1, 256, 0, stream>>>(bh, T3f, Wo, bo, bo2b);

  // the whole 16-step diffusion loop in one persistent kernel
  diffusion_main_kernel<<<128, 512, 0, stream>>>(W0zp, Wfp, baseb, taddb, bo2b, n0, nz, out);
}

// Round 6
// 423.112 us; speedup vs baseline: 1.3240x; 1.3240x over previous
//
#include <hip/hip_runtime.h>

// LESSON (round 3): nontemporal stores to d_out caused stale-L2 readback after
// the harness's 0xAA re-poison -> post-timing divergence. Never nt-store d_out.

typedef __bf16 bf16_t;
typedef bf16_t bf16x8 __attribute__((ext_vector_type(8)));
typedef float f32x4 __attribute__((ext_vector_type(4)));

#define MFMA16(a, b, c) __builtin_amdgcn_mfma_f32_16x16x32_bf16((a), (b), (c), 0, 0, 0)

// async global->LDS, 16B per lane. LDS dest = wave-uniform base + lane*16;
// global src is per-lane (must include lane offset).
__device__ __forceinline__ void glds16(const void* gsrc, void* ldst) {
  __builtin_amdgcn_global_load_lds(
      (const __attribute__((address_space(1))) unsigned int*)gsrc,
      (__attribute__((address_space(3))) unsigned int*)ldst, 16, 0, 0);
}

// ---------------- pack body: KxN f32 -> MFMA B-fragment order (bf16) ----------------
// dst[((kt*NT + nt)*64 + lane)*8 + j] = src[kt*32 + 8*(lane>>4) + j][nt*16 + (lane&15)]
__device__ __forceinline__ void pack_body(const float* __restrict__ src, bf16_t* __restrict__ dst,
                                          int K, int N, int tid0) {
  int NT = N >> 4;
  if (tid0 >= (K >> 5) * NT * 64) return;
  int l = tid0 & 63, grp = tid0 >> 6;
  int nt = grp % NT, kt = grp / NT;
  int rr = l & 15, gg = l >> 4;
  const float* s = src + (size_t)(kt * 32 + 8 * gg) * N + nt * 16 + rr;
  bf16_t* d = dst + (size_t)tid0 * 8;
#pragma unroll
  for (int j = 0; j < 8; ++j) d[j] = (bf16_t)s[(size_t)j * N];
}

// ---------------- P1: fill output constants + casts + packs + tadd ----------------
__global__ __launch_bounds__(256) void p1_kernel(
    const float* __restrict__ r, const float* __restrict__ noise0,
    const float* __restrict__ W0, const float* __restrict__ Wh,
    const float* __restrict__ Wo, const float* __restrict__ Wt, const float* __restrict__ bt,
    bf16_t* __restrict__ r_bf, bf16_t* __restrict__ Wh_bf,
    bf16_t* __restrict__ W0zp, bf16_t* __restrict__ W0rp, bf16_t* __restrict__ Wop,
    float* __restrict__ tadd, float* __restrict__ out)
{
  const int SLAB = 2048 * 256;
  const int SZ = 17 * SLAB;
  int bid = blockIdx.x, tid = threadIdx.x;
  if (bid < 9728) {                                    // fill sigmas / mus[0] / zs[0]
    int i = (bid * 256 + tid) * 4;
    if (i >= 19 * SLAB) return;
    float4 v; int dst;
    if (i < 17 * SLAB) { float x = (i < SLAB) ? 1.0f : 0.25f; v = make_float4(x, x, x, x); dst = 2 * SZ + i; }
    else if (i < 18 * SLAB) { v = make_float4(0.f, 0.f, 0.f, 0.f); dst = SZ + (i - 17 * SLAB); }
    else { v = *(const float4*)(noise0 + (i - 18 * SLAB)); dst = i - 18 * SLAB; }
    *(float4*)(out + dst) = v;
  } else if (bid < 10752) {                            // cast r -> bf16
    int i = ((bid - 9728) * 256 + tid) * 4;
#pragma unroll
    for (int j = 0; j < 4; ++j) r_bf[i + j] = (bf16_t)r[i + j];
  } else if (bid < 11008) {                            // cast Wh -> bf16
    int i = ((bid - 10752) * 256 + tid) * 4;
#pragma unroll
    for (int j = 0; j < 4; ++j) Wh_bf[i + j] = (bf16_t)Wh[i + j];
  } else if (bid < 11072) {                            // pack W0z (K=256, N=512)
    pack_body(W0, W0zp, 256, 512, (bid - 11008) * 256 + tid);
  } else if (bid < 11200) {                            // pack W0r (K=512, N=512)
    pack_body(W0 + 256 * 512, W0rp, 512, 512, (bid - 11072) * 256 + tid);
  } else if (bid < 11264) {                            // pack Wo (K=512, N=256)
    pack_body(Wo, Wop, 512, 256, (bid - 11200) * 256 + tid);
  } else {                                             // tadd[t][n], 32 blocks
    int rel = bid - 11264;
    int t = rel >> 1, n = (rel & 1) * 256 + tid;
    float ts = (t + 1) * 0.0625f;
    float s = 0.f;
#pragma unroll 4
    for (int k = 0; k < 768; ++k) {
      float e = fmaxf(ts * Wt[k] + bt[k], 0.f);
      s = fmaf(e, W0[(size_t)k * 512 + n], s);
    }
    tadd[t * 512 + n] = s;
  }
}

// ---------------- shared GEMM tile: 64x64, 256 threads, A bf16 RM, B packed ----------------
// optional row-major f32 C and/or packed-bf16 Cp (B-fragment order) epilogues
__device__ __forceinline__ void gemm_dev(
    const bf16_t* __restrict__ A, const bf16_t* __restrict__ Bp, const float* __restrict__ bias,
    float* __restrict__ C, bf16_t* __restrict__ Cp,
    int N, int K, int rt, int ct, bool useBias, bool writeRM, bool writePacked)
{
  int tid = threadIdx.x;
  int l = tid & 63, w = tid >> 6;
  int rr = l & 15, gg = l >> 4;
  int rowbase = rt * 64 + w * 16, colbase = ct * 64;
  int NT = N >> 4;
  const bf16x8* Bv = (const bf16x8*)Bp;
  f32x4 acc[4] = {};
  for (int kt = 0; kt < (K >> 5); ++kt) {
    bf16x8 af = *(const bf16x8*)(A + (size_t)(rowbase + rr) * K + kt * 32 + 8 * gg);
#pragma unroll
    for (int nt = 0; nt < 4; ++nt) {
      bf16x8 bf = Bv[(size_t)(kt * NT + (colbase >> 4) + nt) * 64 + l];
      acc[nt] = MFMA16(af, bf, acc[nt]);
    }
  }
#pragma unroll
  for (int nt = 0; nt < 4; ++nt) {
    int col = colbase + nt * 16 + rr;
    float bv = useBias ? bias[col] : 0.f;
#pragma unroll
    for (int q = 0; q < 4; ++q) {
      int row = rowbase + 4 * gg + q;
      float vv = acc[nt][q] + bv;
      if (writeRM) C[(size_t)row * N + col] = vv;
      if (writePacked) {
        // element (row,col) -> packed frag (row>>5)*NT + col>>4, lane', j
        int ktr = row >> 5;
        int lane2 = (2 * (w & 1) + (gg >> 1)) * 16 + rr;   // 8*(lane2>>4)+j == row&31
        int jj = 4 * (gg & 1) + q;
        Cp[(size_t)((ktr * NT + (colbase >> 4) + nt) * 64 + lane2) * 8 + jj] = (bf16_t)vv;
      }
    }
  }
}

// ---------------- P2: base = r@W0r + b0 (256 blks) ; T3 = Wh@Wo (32 blks, RM+packed) ----------------
__global__ __launch_bounds__(256) void p2_kernel(
    const bf16_t* __restrict__ r_bf, const bf16_t* __restrict__ W0rp, const float* __restrict__ b0,
    float* __restrict__ baseb,
    const bf16_t* __restrict__ Wh_bf, const bf16_t* __restrict__ Wop,
    float* __restrict__ T3f, bf16_t* __restrict__ T3p)
{
  int bid = blockIdx.x;
  if (bid < 256) gemm_dev(r_bf, W0rp, b0, baseb, nullptr, 512, 512, bid & 31, bid >> 5, true, true, false);
  else           gemm_dev(Wh_bf, Wop, nullptr, T3f, T3p, 256, 512, (bid - 256) & 7, (bid - 256) >> 3, false, true, true);
}

// ---------------- P3: Wf = Wh@T3 (32 blks, packed only) ; bo2 (1 blk) ----------------
__global__ __launch_bounds__(256) void p3_kernel(
    const bf16_t* __restrict__ Wh_bf, const bf16_t* __restrict__ T3p, bf16_t* __restrict__ Wfp,
    const float* __restrict__ bh, const float* __restrict__ T3f, const float* __restrict__ Wo,
    const float* __restrict__ bo, float* __restrict__ bo2)
{
  int bid = blockIdx.x;
  if (bid < 32) {
    gemm_dev(Wh_bf, T3p, nullptr, nullptr, Wfp, 256, 512, bid & 7, bid >> 3, false, false, true);
  } else {
    int n = threadIdx.x;
    float s = bo[n];
#pragma unroll 4
    for (int k = 0; k < 512; ++k)
      s = fmaf(bh[k], T3f[k * 256 + n] + Wo[k * 256 + n], s);
    bo2[n] = s;
  }
}

// ---------------- main persistent loop ----------------
// 128 WGs x 512 thr, 16 rows/WG, 16 steps. Weights (512KB = W0zp||Wfp) stream
// through a 2x64KB LDS double buffer via global_load_lds: 8 chunks/step
// (0-3 GEMM1 kt-pairs, 4-7 GEMM2 kt-quads), one __syncthreads per chunk.
// The barrier's implicit vmcnt(0) drain + buffer parity give race-free staging:
// stage(c+1) targets buf[(c+1)&1] while compute(c) reads buf[c&1].
__global__ __launch_bounds__(512) void diffusion_main_kernel(
    const bf16_t* __restrict__ wpack,  // [8][32][64][8] W0zp  ||  [16][16][64][8] Wfp
    const float* __restrict__ base,    // [2048][512] = r@W0r + b0
    const float* __restrict__ tadd,    // [16][512]
    const float* __restrict__ bo2,     // [256]
    const float* __restrict__ noise0,  // [2048][256]
    const float* __restrict__ noise,   // [16][2048][256]
    float* __restrict__ out)           // [3][17][2048][256]
{
  __shared__ bf16_t zbuf[16 * 256];
  __shared__ bf16_t abuf[16 * 512];
  __shared__ char wbuf[2][65536];
  const int tid = threadIdx.x;
  const int w = tid >> 6, l = tid & 63;
  const int rr = l & 15, gg = l >> 4;
  const int brow = blockIdx.x << 4;
  const char* wdata = (const char*)wpack;

  // per-lane constants
  f32x4 base_reg[4];
#pragma unroll
  for (int nt = 0; nt < 4; ++nt)
#pragma unroll
    for (int q = 0; q < 4; ++q)
      base_reg[nt][q] = base[(size_t)(brow + 4 * gg + q) * 512 + w * 64 + nt * 16 + rr];
  float bo_reg[2];
#pragma unroll
  for (int nt = 0; nt < 2; ++nt) bo_reg[nt] = bo2[w * 32 + nt * 16 + rr];

  // z state in f32 C-layout regs; wave w owns z cols [w*32, w*32+32)
  f32x4 zst[2];
#pragma unroll
  for (int nt = 0; nt < 2; ++nt)
#pragma unroll
    for (int q = 0; q < 4; ++q)
      zst[nt][q] = noise0[(size_t)(brow + 4 * gg + q) * 256 + w * 32 + nt * 16 + rr];
#pragma unroll
  for (int nt = 0; nt < 2; ++nt)
#pragma unroll
    for (int q = 0; q < 4; ++q) {
      int row = 4 * gg + q, col = w * 32 + nt * 16 + rr;
      zbuf[(row * 256 + col) ^ ((row & 7) << 3)] = (bf16_t)zst[nt][q];
    }

  // stage chunk 0 (64KB): 8 glds of 16B per lane per wave
  {
    const char* src = wdata;
    char* dstl = &wbuf[0][0];
#pragma unroll
    for (int it = 0; it < 8; ++it)
      glds16(src + it * 8192 + w * 1024 + l * 16, dstl + it * 8192 + w * 1024);
  }

  f32x4 acc1[4];
  f32x4 acc2[2];
  bf16x8 zf[8];
  float ep[2][4];
  float tv[4];

#pragma unroll 1
  for (int cc = 0; cc < 128; ++cc) {
    __syncthreads();   // drains this wave's glds (vmcnt 0) + makes all staging/LDS visible
    if (cc + 1 < 128) {
      const char* src = wdata + (size_t)((cc + 1) & 7) * 65536;
      char* dstl = &wbuf[(cc + 1) & 1][0];
#pragma unroll
      for (int it = 0; it < 8; ++it)
        glds16(src + it * 8192 + w * 1024 + l * 16, dstl + it * 8192 + w * 1024);
    }
    const char* wb = &wbuf[cc & 1][0];
    const int ph = cc & 7;
    const int t = cc >> 3;

    if (ph < 4) {
      // ---- GEMM1 chunk: kt = 2*ph, 2*ph+1 ----
      if (ph == 0) {
        // prefetch eps + tadd (consumed at ph==7); load z A-frags; init acc1
#pragma unroll
        for (int nt = 0; nt < 2; ++nt)
#pragma unroll
          for (int q = 0; q < 4; ++q)
            ep[nt][q] = noise[((size_t)t * 2048 + brow + 4 * gg + q) * 256 + w * 32 + nt * 16 + rr];
#pragma unroll
        for (int nt = 0; nt < 4; ++nt) tv[nt] = tadd[t * 512 + w * 64 + nt * 16 + rr];
#pragma unroll
        for (int kt = 0; kt < 8; ++kt) {
          int e = (rr * 256 + kt * 32 + 8 * gg) ^ ((rr & 7) << 3);
          zf[kt] = *(const bf16x8*)&zbuf[e];
        }
#pragma unroll
        for (int nt = 0; nt < 4; ++nt)
#pragma unroll
          for (int q = 0; q < 4; ++q) acc1[nt][q] = base_reg[nt][q] + tv[nt];
      }
#pragma unroll
      for (int ktl = 0; ktl < 2; ++ktl) {
        int fbase = ktl * 32 + w * 4;
#pragma unroll
        for (int nt = 0; nt < 4; ++nt) {
          bf16x8 wfrag = *(const bf16x8*)(wb + ((size_t)(fbase + nt) * 64 + l) * 16);
          acc1[nt] = MFMA16(zf[2 * ph + ktl], wfrag, acc1[nt]);
        }
      }
      if (ph == 3) {
        // a = relu(h1) -> abuf (bf16, XOR-swizzled); visible after next barrier
#pragma unroll
        for (int nt = 0; nt < 4; ++nt)
#pragma unroll
          for (int q = 0; q < 4; ++q) {
            int row = 4 * gg + q, col = w * 64 + nt * 16 + rr;
            abuf[(row * 512 + col) ^ ((row & 7) << 3)] = (bf16_t)fmaxf(acc1[nt][q], 0.f);
          }
      }
    } else {
      // ---- GEMM2 chunk: kt = 4*(ph-4) .. +3 ----
      if (ph == 4) {
#pragma unroll
        for (int nt = 0; nt < 2; ++nt)
#pragma unroll
          for (int q = 0; q < 4; ++q) acc2[nt][q] = bo_reg[nt];
      }
      const int pc = ph - 4;
#pragma unroll
      for (int ktl = 0; ktl < 4; ++ktl) {
        int ktg = pc * 4 + ktl;
        int e = (rr * 512 + ktg * 32 + 8 * gg) ^ ((rr & 7) << 3);
        bf16x8 afr = *(const bf16x8*)&abuf[e];
        int fbase = ktl * 16 + w * 2;
#pragma unroll
        for (int nt = 0; nt < 2; ++nt) {
          bf16x8 wfrag = *(const bf16x8*)(wb + ((size_t)(fbase + nt) * 64 + l) * 16);
          acc2[nt] = MFMA16(afr, wfrag, acc2[nt]);
        }
      }
      if (ph == 7) {
        // z update + write zs[t+1], mus[t+1] (plain stores — see nt-store lesson)
#pragma unroll
        for (int nt = 0; nt < 2; ++nt)
#pragma unroll
          for (int q = 0; q < 4; ++q) {
            int row = 4 * gg + q, col = w * 32 + nt * 16 + rr;
            int grow = brow + row;
            float mu = fmaf(acc2[nt][q], 0.0625f, zst[nt][q]);
            float zn = fmaf(ep[nt][q], 0.25f, mu);
            zst[nt][q] = zn;
            out[((size_t)(t + 1) * 2048 + grow) * 256 + col] = zn;
            out[((size_t)(17 + t + 1) * 2048 + grow) * 256 + col] = mu;
            zbuf[(row * 256 + col) ^ ((row & 7) << 3)] = (bf16_t)zn;
          }
      }
    }
  }
}

extern "C" void kernel_launch(void* const* d_in, const int* in_sizes, int n_in,
                              void* d_out, int out_size, void* d_ws, size_t ws_size,
                              hipStream_t stream) {
  const float* r   = (const float*)d_in[0];
  const float* n0  = (const float*)d_in[1];
  const float* nz  = (const float*)d_in[2];
  const float* W0  = (const float*)d_in[3];
  const float* b0  = (const float*)d_in[4];
  const float* Wh  = (const float*)d_in[5];
  const float* bh  = (const float*)d_in[6];
  const float* Wo  = (const float*)d_in[7];
  const float* bo  = (const float*)d_in[8];
  const float* Wt  = (const float*)d_in[9];
  const float* bt  = (const float*)d_in[10];
  float* out = (float*)d_out;

  char* ws = (char*)d_ws;
  size_t off = 0;
  auto alloc = [&](size_t bytes) -> char* {
    char* p = ws + off;
    off += (bytes + 255) & ~(size_t)255;
    return p;
  };
  bf16_t* r_bf  = (bf16_t*)alloc((size_t)2048 * 512 * 2);
  bf16_t* Wh_bf = (bf16_t*)alloc((size_t)512 * 512 * 2);
  bf16_t* wpack = (bf16_t*)alloc((size_t)512 * 1024);        // W0zp (256KB) || Wfp (256KB)
  bf16_t* W0zp  = wpack;
  bf16_t* Wfp   = wpack + 131072;
  bf16_t* W0rp  = (bf16_t*)alloc((size_t)512 * 512 * 2);
  bf16_t* Wop   = (bf16_t*)alloc((size_t)512 * 256 * 2);
  float*  T3f   = (float*) alloc((size_t)512 * 256 * 4);
  bf16_t* T3p   = (bf16_t*)alloc((size_t)512 * 256 * 2);
  float*  baseb = (float*) alloc((size_t)2048 * 512 * 4);
  float*  taddb = (float*) alloc((size_t)16 * 512 * 4);
  float*  bo2b  = (float*) alloc((size_t)256 * 4);
  if (off > ws_size) return;

  // P1: fill + casts + packs + tadd (independent prep, one launch)
  p1_kernel<<<11296, 256, 0, stream>>>(r, n0, W0, Wh, Wo, Wt, bt,
                                       r_bf, Wh_bf, W0zp, W0rp, Wop, taddb, out);
  // P2: base GEMM + T3 GEMM (row-major + packed epilogue)
  p2_kernel<<<288, 256, 0, stream>>>(r_bf, W0rp, b0, baseb, Wh_bf, Wop, T3f, T3p);
  // P3: Wf GEMM (packed) + bo2
  p3_kernel<<<33, 256, 0, stream>>>(Wh_bf, T3p, Wfp, bh, T3f, Wo, bo, bo2b);
  // main 16-step loop
  diffusion_main_kernel<<<128, 512, 0, stream>>>(wpack, baseb, taddb, bo2b, n0, nz, out);
}